// Round 19
// baseline (212.171 us; speedup 1.0000x reference)
//
#include <hip/hip_runtime.h>

// CAM module: fused split (x -> i8 a/b split + bf16 xt transpose); energy = q qT via
// EXACT integer i8x2 MFMA (4 products); softmin -> bf16 attn;
// out = gamma*(attn q) + x (128x128 bf16, 2-buffer; x prefetched under K-loop tail).
// B=16, C=512, N=64*64=4096

#define BATCH 16
#define CCH   512
#define NSP   4096

typedef __attribute__((ext_vector_type(8))) short bfx8;
typedef __attribute__((ext_vector_type(4))) float fx4;
typedef __attribute__((ext_vector_type(2))) float fx2;
typedef __attribute__((ext_vector_type(4))) int   ix4;

__device__ __forceinline__ short f2bf(float v) {
    union { float f; unsigned u; } a; a.f = v;
    unsigned r = a.u + 0x7fffu + ((a.u >> 16) & 1u);   // RNE
    return (short)(r >> 16);
}

// async global(16B/lane) -> LDS (wave-uniform base + lane*16)
__device__ __forceinline__ void gload16(const short* g, short* l) {
    __builtin_amdgcn_global_load_lds((const __attribute__((address_space(1))) void*)g,
                                     (__attribute__((address_space(3))) void*)l, 16, 0, 0);
}
__device__ __forceinline__ void gload16c(const char* g, char* l) {
    __builtin_amdgcn_global_load_lds((const __attribute__((address_space(1))) void*)g,
                                     (__attribute__((address_space(3))) void*)l, 16, 0, 0);
}

// ---------------- Kernel 0: x -> xa,xb (i8 split, x ~ (a*128+b)*2^-11) + xt (bf16 [n][c]) ----
__global__ __launch_bounds__(256) void fused_split_kernel(const float* __restrict__ x,
                                                          char* __restrict__ xa,
                                                          char* __restrict__ xb,
                                                          short* __restrict__ xt) {
    int blk = blockIdx.x;              // 16*8*64 = 8192
    int b  = blk >> 9;
    int t  = blk & 511;
    int ct = t >> 6;                   // c-tile 0..7
    int nt = t & 63;                   // n-tile 0..63
    int c0 = ct * 64, n0 = nt * 64;
    const float* xbp = x  + (size_t)b * CCH * NSP;
    char*        xab = xa + (size_t)b * CCH * NSP;
    char*        xbb = xb + (size_t)b * CCH * NSP;
    short*       xtb = xt + (size_t)b * NSP * CCH;

    __shared__ short A[64][64];        // [c][n] bf16, chunk ch at slot ch^(c&7)
    __shared__ short Bn[64][64];       // [n][c] bf16, chunk dr at slot dr^((n>>1)&7)

    int tid = threadIdx.x;

    // phase 1: read x rows, quantize -> xa/xb (coalesced), stash bf16 h in LDS A
#pragma unroll
    for (int s = 0; s < 2; ++s) {
        int idx = s * 256 + tid;
        int row = idx >> 3;            // c-row 0..63
        int ch  = idx & 7;             // n-chunk
        const float* p = xbp + (size_t)(c0 + row) * NSP + n0 + ch * 8;
        fx4 v0 = *(const fx4*)p;
        fx4 v1 = *(const fx4*)(p + 4);
        int av[8], bv[8];
        bfx8 h;
#pragma unroll
        for (int e = 0; e < 4; ++e) {
            float xv = v0[e];
            h[e] = f2bf(xv);
            float xs = fminf(fmaxf(xv * 2048.0f, -16384.0f), 16319.0f);
            int q = __float2int_rn(xs);
            int aq = (q + 64) >> 7;
            av[e] = aq; bv[e] = q - (aq << 7);
            xv = v1[e];
            h[e + 4] = f2bf(xv);
            xs = fminf(fmaxf(xv * 2048.0f, -16384.0f), 16319.0f);
            q = __float2int_rn(xs);
            aq = (q + 64) >> 7;
            av[e + 4] = aq; bv[e + 4] = q - (aq << 7);
        }
        unsigned pa0 = (unsigned)(av[0] & 255) | ((unsigned)(av[1] & 255) << 8) |
                       ((unsigned)(av[2] & 255) << 16) | ((unsigned)(av[3] & 255) << 24);
        unsigned pa1 = (unsigned)(av[4] & 255) | ((unsigned)(av[5] & 255) << 8) |
                       ((unsigned)(av[6] & 255) << 16) | ((unsigned)(av[7] & 255) << 24);
        unsigned pb0 = (unsigned)(bv[0] & 255) | ((unsigned)(bv[1] & 255) << 8) |
                       ((unsigned)(bv[2] & 255) << 16) | ((unsigned)(bv[3] & 255) << 24);
        unsigned pb1 = (unsigned)(bv[4] & 255) | ((unsigned)(bv[5] & 255) << 8) |
                       ((unsigned)(bv[6] & 255) << 16) | ((unsigned)(bv[7] & 255) << 24);
        size_t go = (size_t)(c0 + row) * NSP + n0 + ch * 8;
        ((unsigned*)(xab + go))[0] = pa0; ((unsigned*)(xab + go))[1] = pa1;
        ((unsigned*)(xbb + go))[0] = pb0; ((unsigned*)(xbb + go))[1] = pb1;
        *(bfx8*)(&A[row][(ch ^ (row & 7)) * 8]) = h;
    }
    __syncthreads();

    // phase 2a: u32 column gather (n-pair 2p,2p+1 across 8 c-rows)
    int p  = tid & 31;
    int dr = tid >> 5;                 // c-oct 0..7
    unsigned wv[8];
#pragma unroll
    for (int i = 0; i < 8; ++i) {
        int r = dr * 8 + i;
        int byte = r * 128 + ((((p >> 2) ^ (r & 7)) * 8 + (2 * p & 7)) * 2);
        wv[i] = *(const unsigned*)((const char*)&A[0][0] + byte);
    }
    bfx8 q0, q1;
#pragma unroll
    for (int i = 0; i < 8; ++i) { q0[i] = (short)(wv[i] & 0xffff); q1[i] = (short)(wv[i] >> 16); }

    int slot2 = dr ^ (p & 7);
    *(bfx8*)(&Bn[2 * p][slot2 * 8])     = q0;
    *(bfx8*)(&Bn[2 * p + 1][slot2 * 8]) = q1;
    __syncthreads();

    // phase 2c: coalesced xt row writes (non-temporal)
#pragma unroll
    for (int it = 0; it < 2; ++it) {
        int n  = it * 32 + (tid >> 3);
        int ch = tid & 7;
        bfx8 v = *(const bfx8*)(&Bn[n][(ch ^ ((n >> 1) & 7)) * 8]);
        __builtin_nontemporal_store(v, (bfx8*)(xtb + (size_t)(n0 + n) * CCH + c0 + ch * 8));
    }
}

// ---------------- Kernel 1: energy = q qT, i8x2 EXACT (4 products), symmetric tiles ----------
// 64x64 tile, 4 waves (32x32), BK=64, dbuf 32 KiB. LDS rows packed as [32 pairs][128B],
// slot = (kg + 4*(r&1)) ^ (p&7) -> frag reads perfectly bank-uniform (verified).
__global__ __launch_bounds__(256) void energy_kernel(const char* __restrict__ xa,
                                                     const char* __restrict__ xb,
                                                     float* __restrict__ energy) {
    int orig = blockIdx.x;
    int wgid = (orig & 7) * 72 + (orig >> 3);   // 576 = 8 xcds x 72
    int b = wgid / 36;
    int t = wgid % 36;
    int ti = 0, rem = t;
    while (rem >= 8 - ti) { rem -= 8 - ti; ++ti; }
    int tj = ti + rem;
    int c0 = ti * 64, d0 = tj * 64;
    bool diag = (ti == tj);
    const char* pa = xa + (size_t)b * CCH * NSP;
    const char* pb = xb + (size_t)b * CCH * NSP;

    __shared__ char S[2][4][32][128];   // [buf][Aa,Ab,Ba,Bb][pair][byte] = 32 KiB

    int tid  = threadIdx.x;
    int lane = tid & 63;
    int w    = tid >> 6;
    int wr   = (w >> 1) * 32;
    int wc   = (w & 1) * 32;

    int pp  = lane >> 3;
    int e0i = (lane & 7) ^ pp;
    int ehi = e0i >> 2, kg = e0i & 3;
    const char* ssrc = (w & 1) ? pb : pa;
    int rbase = (w >= 2) ? d0 : c0;
    bool doStage = (w < 2) || !diag;

    auto STAGE = [&](int buf, int kt) {
        if (!doStage) return;
#pragma unroll
        for (int s = 0; s < 4; ++s) {
            int r = 16 * s + 2 * pp + ehi;
            gload16c(ssrc + (size_t)(rbase + r) * NSP + kt * 64 + kg * 16, &S[buf][w][s * 8][0]);
        }
    };

    ix4 acc1[2][2], acc2[2][2], acc3[2][2];
#pragma unroll
    for (int i = 0; i < 2; i++)
#pragma unroll
        for (int j = 0; j < 2; j++) { acc1[i][j] = (ix4)(0); acc2[i][j] = (ix4)(0); acc3[i][j] = (ix4)(0); }

    STAGE(0, 0);
    __syncthreads();

    int m = lane & 15, kgrp = lane >> 4;
    int slot16 = (((kgrp + 4 * (m & 1)) ^ (m >> 1)) << 4);
    int phalf  = m >> 1;
    int aBa = diag ? 0 : 2, aBb = diag ? 1 : 3;

    int cur = 0;
    const int NT = NSP / 64;            // 64
    for (int kt = 0; kt < NT; ++kt) {
        ix4 faa[2], fab[2], fba[2], fbb[2];
#pragma unroll
        for (int mi = 0; mi < 2; ++mi) {
            int p = (wr >> 1) + mi * 8 + phalf;
            faa[mi] = *(const ix4*)&S[cur][0][p][slot16];
            fab[mi] = *(const ix4*)&S[cur][1][p][slot16];
        }
#pragma unroll
        for (int ni = 0; ni < 2; ++ni) {
            int p = (wc >> 1) + ni * 8 + phalf;
            fba[ni] = *(const ix4*)&S[cur][aBa][p][slot16];
            fbb[ni] = *(const ix4*)&S[cur][aBb][p][slot16];
        }
        if (kt + 1 < NT) STAGE(cur ^ 1, kt + 1);
        __builtin_amdgcn_s_setprio(1);
#pragma unroll
        for (int mi = 0; mi < 2; ++mi)
#pragma unroll
            for (int ni = 0; ni < 2; ++ni) {
                acc1[mi][ni] = __builtin_amdgcn_mfma_i32_16x16x64_i8(faa[mi], fba[ni], acc1[mi][ni], 0, 0, 0);
                acc2[mi][ni] = __builtin_amdgcn_mfma_i32_16x16x64_i8(faa[mi], fbb[ni], acc2[mi][ni], 0, 0, 0);
                acc2[mi][ni] = __builtin_amdgcn_mfma_i32_16x16x64_i8(fab[mi], fba[ni], acc2[mi][ni], 0, 0, 0);
                acc3[mi][ni] = __builtin_amdgcn_mfma_i32_16x16x64_i8(fab[mi], fbb[ni], acc3[mi][ni], 0, 0, 0);
            }
        __builtin_amdgcn_s_setprio(0);
        __syncthreads();
        cur ^= 1;
    }

    // e = S_aa*2^-8 + (S_ab+S_ba)*2^-15 + S_bb*2^-22  (exact in quantized domain)
    int colw = lane & 15;
    int rowg = (lane >> 4) * 4;
#pragma unroll
    for (int mi = 0; mi < 2; ++mi)
#pragma unroll
        for (int ni = 0; ni < 2; ++ni) {
            int cb = c0 + wr + mi * 16 + rowg;
            int d  = d0 + wc + ni * 16 + colw;
#pragma unroll
            for (int r = 0; r < 4; ++r) {
                int c = cb + r;
                float v = (float)acc1[mi][ni][r] * 0.00390625f
                        + (float)acc2[mi][ni][r] * 3.0517578125e-05f
                        + (float)acc3[mi][ni][r] * 2.384185791015625e-07f;
                energy[((size_t)b * CCH + c) * CCH + d] = v;
                if (!diag)
                    energy[((size_t)b * CCH + d) * CCH + c] = v;
            }
        }
}

// ---------------- Kernel 2: softmin over rows; writes bf16 attn in-place ----------------
__global__ __launch_bounds__(256) void softmax_kernel(float* __restrict__ energy) {
    size_t row = blockIdx.x;
    float* e = energy + row * CCH;
    int tid = threadIdx.x;
    fx2 v = *(const fx2*)(e + 2 * tid);

    float m = fminf(v[0], v[1]);
#pragma unroll
    for (int off = 32; off; off >>= 1) m = fminf(m, __shfl_xor(m, off));
    __shared__ float redm[4];
    __shared__ float reds[4];
    if ((tid & 63) == 0) redm[tid >> 6] = m;
    __syncthreads();
    m = fminf(fminf(redm[0], redm[1]), fminf(redm[2], redm[3]));

    float w0 = __expf(m - v[0]);
    float w1 = __expf(m - v[1]);
    float s = w0 + w1;
#pragma unroll
    for (int off = 32; off; off >>= 1) s += __shfl_xor(s, off);
    if ((tid & 63) == 0) reds[tid >> 6] = s;
    __syncthreads();
    s = (reds[0] + reds[1]) + (reds[2] + reds[3]);
    float inv = 1.0f / s;
    unsigned uw = ((unsigned)(unsigned short)f2bf(w0 * inv)) |
                  (((unsigned)(unsigned short)f2bf(w1 * inv)) << 16);
    ((unsigned*)e)[tid] = uw;   // safe: all reads completed before barriers
}

// ---------------- Kernel 3: out = gamma * (attn @ q) + x ----------------
// 128x128 tile, BK=32, 4 waves each owning 64x64. 2-buffer (32 KiB) -> 4 blocks/CU.
// x half-tile prefetched inside the last K-iteration (rides the existing vmcnt drain);
// final barrier removed; epilogue: issue remaining x loads, then nontemporal stores.
__global__ __launch_bounds__(256, 4) void out_kernel(const float* __restrict__ x,
                                                     const short* __restrict__ attnb, // 1024-short rows
                                                     const short* __restrict__ xt,    // [n][c] bf16
                                                     const float* __restrict__ gamma,
                                                     float* __restrict__ out) {
    int orig = blockIdx.x;
    int blk  = (orig & 7) * 256 + (orig >> 3);   // 2048 = 8 x 256
    int b   = blk >> 7;
    int t   = blk & 127;
    int c0  = (t >> 5) * 128;
    int n0  = (t & 31) * 128;
    const float* xb = x + (size_t)b * CCH * NSP;
    const short* ab = attnb + (size_t)b * CCH * 1024;
    const short* qt = xt + (size_t)b * NSP * CCH;

    __shared__ short SA[2][128][32];    // 16 KiB
    __shared__ short SB[2][128][32];    // 16 KiB

    int tid  = threadIdx.x;
    int lane = tid & 63;
    int w    = tid >> 6;
    int wr   = (w >> 1) * 64;
    int wc   = (w & 1) * 64;

    int colw = lane & 15;
    int rowg = (lane >> 4) * 4;

    int srow = lane >> 2;
    int gch  = (lane & 3) ^ ((lane >> 3) & 3);

    auto STAGE = [&](int buf, int kt) {
#pragma unroll
        for (int hf = 0; hf < 2; ++hf) {
            int rg = hf * 64 + w * 16;
            gload16(ab + (size_t)(c0 + rg + srow) * 1024 + kt * 32 + gch * 8, &SA[buf][rg][0]);
            gload16(qt + (size_t)(n0 + rg + srow) * 512  + kt * 32 + gch * 8, &SB[buf][rg][0]);
        }
    };

    fx4 acc[4][4];
#pragma unroll
    for (int i = 0; i < 4; i++)
#pragma unroll
        for (int j = 0; j < 4; j++) acc[i][j] = (fx4)(0.0f);

    STAGE(0, 0);
    __syncthreads();

    float xv0[2][4][4];                 // x prefetch for mi 0..1 (static-indexed)

    int h = lane >> 4;
    int cur = 0;
    const int NT = CCH / 32;            // 16
    for (int kt = 0; kt < NT; ++kt) {
        // issue next tile's loads first (max flight time under this step's MFMA)
        if (kt + 1 < NT) STAGE(cur ^ 1, kt + 1);

        bfx8 af[4], bf[4];
#pragma unroll
        for (int mi = 0; mi < 4; ++mi) {
            int r  = wr + mi * 16 + (lane & 15);
            af[mi] = *(const bfx8*)((const char*)&SA[cur][0][0] + r * 64 + ((h ^ ((r >> 1) & 3)) << 4));
        }
#pragma unroll
        for (int ni = 0; ni < 4; ++ni) {
            int r  = wc + ni * 16 + (lane & 15);
            bf[ni] = *(const bfx8*)((const char*)&SB[cur][0][0] + r * 64 + ((h ^ ((r >> 1) & 3)) << 4));
        }
        if (kt == NT - 1) {
            // prefetch x for mi 0..1 — hidden under the final MFMA block (no barrier after)
#pragma unroll
            for (int mi = 0; mi < 2; ++mi)
#pragma unroll
                for (int r = 0; r < 4; ++r) {
                    const float* xrowp = xb + (size_t)(c0 + wr + mi * 16 + rowg + r) * NSP;
#pragma unroll
                    for (int ni = 0; ni < 4; ++ni)
                        xv0[mi][r][ni] = xrowp[n0 + wc + ni * 16 + colw];
                }
        }
        __builtin_amdgcn_s_setprio(1);
#pragma unroll
        for (int mi = 0; mi < 4; ++mi)
#pragma unroll
            for (int ni = 0; ni < 4; ++ni)
                acc[mi][ni] = __builtin_amdgcn_mfma_f32_16x16x32_bf16(af[mi], bf[ni], acc[mi][ni], 0, 0, 0);
        __builtin_amdgcn_s_setprio(0);
        if (kt + 1 < NT) __syncthreads();   // final barrier unnecessary (LDS dead after)
        cur ^= 1;
    }

    float g = gamma[0];

    // issue remaining x loads (mi 2..3) — covered by the mi 0..1 store stream
    float xv1[2][4][4];
#pragma unroll
    for (int mi = 0; mi < 2; ++mi)
#pragma unroll
        for (int r = 0; r < 4; ++r) {
            const float* xrowp = xb + (size_t)(c0 + wr + (mi + 2) * 16 + rowg + r) * NSP;
#pragma unroll
            for (int ni = 0; ni < 4; ++ni)
                xv1[mi][r][ni] = xrowp[n0 + wc + ni * 16 + colw];
        }

#pragma unroll
    for (int mi = 0; mi < 2; ++mi)
#pragma unroll
        for (int r = 0; r < 4; ++r) {
            int c = c0 + wr + mi * 16 + rowg + r;
#pragma unroll
            for (int ni = 0; ni < 4; ++ni) {
                int n = n0 + wc + ni * 16 + colw;
                __builtin_nontemporal_store(g * acc[mi][ni][r] + xv0[mi][r][ni],
                                            &out[((size_t)b * CCH + c) * NSP + n]);
            }
        }
#pragma unroll
    for (int mi = 0; mi < 2; ++mi)
#pragma unroll
        for (int r = 0; r < 4; ++r) {
            int c = c0 + wr + (mi + 2) * 16 + rowg + r;
#pragma unroll
            for (int ni = 0; ni < 4; ++ni) {
                int n = n0 + wc + ni * 16 + colw;
                __builtin_nontemporal_store(g * acc[mi + 2][ni][r] + xv1[mi][r][ni],
                                            &out[((size_t)b * CCH + c) * NSP + n]);
            }
        }
}

extern "C" void kernel_launch(void* const* d_in, const int* in_sizes, int n_in,
                              void* d_out, int out_size, void* d_ws, size_t ws_size,
                              hipStream_t stream) {
    (void)in_sizes; (void)n_in; (void)out_size; (void)ws_size;
    const float* x     = (const float*)d_in[0];
    const float* gamma = (const float*)d_in[1];
    float*       out   = (float*)d_out;

    size_t nel = (size_t)BATCH * CCH * NSP;              // 33.5M
    // ws layout: xa(nel) | xb(nel) | xt(2*nel) | e0(16.8MB) = 151 MB
    char*  xap = (char*)d_ws;
    char*  xbp = xap + nel;
    short* xtp = (short*)(xap + 2 * nel);
    float* e0  = (float*)(xap + 4 * nel);

    fused_split_kernel<<<BATCH * 512, 256, 0, stream>>>(x, xap, xbp, xtp);
    energy_kernel     <<<BATCH * 36, 256, 0, stream>>>(xap, xbp, e0);
    softmax_kernel    <<<BATCH * CCH, 256, 0, stream>>>(e0);
    out_kernel        <<<BATCH * 128, 256, 0, stream>>>(x, (const short*)e0, xtp, gamma, out);
}

// Round 20
// 196.837 us; speedup vs baseline: 1.0779x; 1.0779x over previous
//
#include <hip/hip_runtime.h>

// CAM module: fused split (x -> i8 a/b split + bf16 xt transpose); energy = q qT via
// EXACT integer i8x2 MFMA (4 products); softmin -> bf16 attn;
// out = gamma*(attn q) + x (128x128 bf16, 2-buffer, 4 blocks/CU; 16-wide batched epilogue).
// B=16, C=512, N=64*64=4096

#define BATCH 16
#define CCH   512
#define NSP   4096

typedef __attribute__((ext_vector_type(8))) short bfx8;
typedef __attribute__((ext_vector_type(4))) float fx4;
typedef __attribute__((ext_vector_type(2))) float fx2;
typedef __attribute__((ext_vector_type(4))) int   ix4;

__device__ __forceinline__ short f2bf(float v) {
    union { float f; unsigned u; } a; a.f = v;
    unsigned r = a.u + 0x7fffu + ((a.u >> 16) & 1u);   // RNE
    return (short)(r >> 16);
}

// async global(16B/lane) -> LDS (wave-uniform base + lane*16)
__device__ __forceinline__ void gload16(const short* g, short* l) {
    __builtin_amdgcn_global_load_lds((const __attribute__((address_space(1))) void*)g,
                                     (__attribute__((address_space(3))) void*)l, 16, 0, 0);
}
__device__ __forceinline__ void gload16c(const char* g, char* l) {
    __builtin_amdgcn_global_load_lds((const __attribute__((address_space(1))) void*)g,
                                     (__attribute__((address_space(3))) void*)l, 16, 0, 0);
}

// ---------------- Kernel 0: x -> xa,xb (i8 split, x ~ (a*128+b)*2^-11) + xt (bf16 [n][c]) ----
__global__ __launch_bounds__(256) void fused_split_kernel(const float* __restrict__ x,
                                                          char* __restrict__ xa,
                                                          char* __restrict__ xb,
                                                          short* __restrict__ xt) {
    int blk = blockIdx.x;              // 16*8*64 = 8192
    int b  = blk >> 9;
    int t  = blk & 511;
    int ct = t >> 6;                   // c-tile 0..7
    int nt = t & 63;                   // n-tile 0..63
    int c0 = ct * 64, n0 = nt * 64;
    const float* xbp = x  + (size_t)b * CCH * NSP;
    char*        xab = xa + (size_t)b * CCH * NSP;
    char*        xbb = xb + (size_t)b * CCH * NSP;
    short*       xtb = xt + (size_t)b * NSP * CCH;

    __shared__ short A[64][64];        // [c][n] bf16, chunk ch at slot ch^(c&7)
    __shared__ short Bn[64][64];       // [n][c] bf16, chunk dr at slot dr^((n>>1)&7)

    int tid = threadIdx.x;

    // phase 1: read x rows, quantize -> xa/xb (coalesced), stash bf16 h in LDS A
#pragma unroll
    for (int s = 0; s < 2; ++s) {
        int idx = s * 256 + tid;
        int row = idx >> 3;            // c-row 0..63
        int ch  = idx & 7;             // n-chunk
        const float* p = xbp + (size_t)(c0 + row) * NSP + n0 + ch * 8;
        fx4 v0 = *(const fx4*)p;
        fx4 v1 = *(const fx4*)(p + 4);
        int av[8], bv[8];
        bfx8 h;
#pragma unroll
        for (int e = 0; e < 4; ++e) {
            float xv = v0[e];
            h[e] = f2bf(xv);
            float xs = fminf(fmaxf(xv * 2048.0f, -16384.0f), 16319.0f);
            int q = __float2int_rn(xs);
            int aq = (q + 64) >> 7;
            av[e] = aq; bv[e] = q - (aq << 7);
            xv = v1[e];
            h[e + 4] = f2bf(xv);
            xs = fminf(fmaxf(xv * 2048.0f, -16384.0f), 16319.0f);
            q = __float2int_rn(xs);
            aq = (q + 64) >> 7;
            av[e + 4] = aq; bv[e + 4] = q - (aq << 7);
        }
        unsigned pa0 = (unsigned)(av[0] & 255) | ((unsigned)(av[1] & 255) << 8) |
                       ((unsigned)(av[2] & 255) << 16) | ((unsigned)(av[3] & 255) << 24);
        unsigned pa1 = (unsigned)(av[4] & 255) | ((unsigned)(av[5] & 255) << 8) |
                       ((unsigned)(av[6] & 255) << 16) | ((unsigned)(av[7] & 255) << 24);
        unsigned pb0 = (unsigned)(bv[0] & 255) | ((unsigned)(bv[1] & 255) << 8) |
                       ((unsigned)(bv[2] & 255) << 16) | ((unsigned)(bv[3] & 255) << 24);
        unsigned pb1 = (unsigned)(bv[4] & 255) | ((unsigned)(bv[5] & 255) << 8) |
                       ((unsigned)(bv[6] & 255) << 16) | ((unsigned)(bv[7] & 255) << 24);
        size_t go = (size_t)(c0 + row) * NSP + n0 + ch * 8;
        ((unsigned*)(xab + go))[0] = pa0; ((unsigned*)(xab + go))[1] = pa1;
        ((unsigned*)(xbb + go))[0] = pb0; ((unsigned*)(xbb + go))[1] = pb1;
        *(bfx8*)(&A[row][(ch ^ (row & 7)) * 8]) = h;
    }
    __syncthreads();

    // phase 2a: u32 column gather (n-pair 2p,2p+1 across 8 c-rows)
    int p  = tid & 31;
    int dr = tid >> 5;                 // c-oct 0..7
    unsigned wv[8];
#pragma unroll
    for (int i = 0; i < 8; ++i) {
        int r = dr * 8 + i;
        int byte = r * 128 + ((((p >> 2) ^ (r & 7)) * 8 + (2 * p & 7)) * 2);
        wv[i] = *(const unsigned*)((const char*)&A[0][0] + byte);
    }
    bfx8 q0, q1;
#pragma unroll
    for (int i = 0; i < 8; ++i) { q0[i] = (short)(wv[i] & 0xffff); q1[i] = (short)(wv[i] >> 16); }

    int slot2 = dr ^ (p & 7);
    *(bfx8*)(&Bn[2 * p][slot2 * 8])     = q0;
    *(bfx8*)(&Bn[2 * p + 1][slot2 * 8]) = q1;
    __syncthreads();

    // phase 2c: coalesced xt row writes (non-temporal)
#pragma unroll
    for (int it = 0; it < 2; ++it) {
        int n  = it * 32 + (tid >> 3);
        int ch = tid & 7;
        bfx8 v = *(const bfx8*)(&Bn[n][(ch ^ ((n >> 1) & 7)) * 8]);
        __builtin_nontemporal_store(v, (bfx8*)(xtb + (size_t)(n0 + n) * CCH + c0 + ch * 8));
    }
}

// ---------------- Kernel 1: energy = q qT, i8x2 EXACT (4 products), symmetric tiles ----------
// 64x64 tile, 4 waves (32x32), BK=64, dbuf 32 KiB. LDS rows packed as [32 pairs][128B],
// slot = (kg + 4*(r&1)) ^ (p&7) -> frag reads perfectly bank-uniform (verified).
__global__ __launch_bounds__(256) void energy_kernel(const char* __restrict__ xa,
                                                     const char* __restrict__ xb,
                                                     float* __restrict__ energy) {
    int orig = blockIdx.x;
    int wgid = (orig & 7) * 72 + (orig >> 3);   // 576 = 8 xcds x 72
    int b = wgid / 36;
    int t = wgid % 36;
    int ti = 0, rem = t;
    while (rem >= 8 - ti) { rem -= 8 - ti; ++ti; }
    int tj = ti + rem;
    int c0 = ti * 64, d0 = tj * 64;
    bool diag = (ti == tj);
    const char* pa = xa + (size_t)b * CCH * NSP;
    const char* pb = xb + (size_t)b * CCH * NSP;

    __shared__ char S[2][4][32][128];   // [buf][Aa,Ab,Ba,Bb][pair][byte] = 32 KiB

    int tid  = threadIdx.x;
    int lane = tid & 63;
    int w    = tid >> 6;
    int wr   = (w >> 1) * 32;
    int wc   = (w & 1) * 32;

    int pp  = lane >> 3;
    int e0i = (lane & 7) ^ pp;
    int ehi = e0i >> 2, kg = e0i & 3;
    const char* ssrc = (w & 1) ? pb : pa;
    int rbase = (w >= 2) ? d0 : c0;
    bool doStage = (w < 2) || !diag;

    auto STAGE = [&](int buf, int kt) {
        if (!doStage) return;
#pragma unroll
        for (int s = 0; s < 4; ++s) {
            int r = 16 * s + 2 * pp + ehi;
            gload16c(ssrc + (size_t)(rbase + r) * NSP + kt * 64 + kg * 16, &S[buf][w][s * 8][0]);
        }
    };

    ix4 acc1[2][2], acc2[2][2], acc3[2][2];
#pragma unroll
    for (int i = 0; i < 2; i++)
#pragma unroll
        for (int j = 0; j < 2; j++) { acc1[i][j] = (ix4)(0); acc2[i][j] = (ix4)(0); acc3[i][j] = (ix4)(0); }

    STAGE(0, 0);
    __syncthreads();

    int m = lane & 15, kgrp = lane >> 4;
    int slot16 = (((kgrp + 4 * (m & 1)) ^ (m >> 1)) << 4);
    int phalf  = m >> 1;
    int aBa = diag ? 0 : 2, aBb = diag ? 1 : 3;

    int cur = 0;
    const int NT = NSP / 64;            // 64
    for (int kt = 0; kt < NT; ++kt) {
        ix4 faa[2], fab[2], fba[2], fbb[2];
#pragma unroll
        for (int mi = 0; mi < 2; ++mi) {
            int p = (wr >> 1) + mi * 8 + phalf;
            faa[mi] = *(const ix4*)&S[cur][0][p][slot16];
            fab[mi] = *(const ix4*)&S[cur][1][p][slot16];
        }
#pragma unroll
        for (int ni = 0; ni < 2; ++ni) {
            int p = (wc >> 1) + ni * 8 + phalf;
            fba[ni] = *(const ix4*)&S[cur][aBa][p][slot16];
            fbb[ni] = *(const ix4*)&S[cur][aBb][p][slot16];
        }
        if (kt + 1 < NT) STAGE(cur ^ 1, kt + 1);
        __builtin_amdgcn_s_setprio(1);
#pragma unroll
        for (int mi = 0; mi < 2; ++mi)
#pragma unroll
            for (int ni = 0; ni < 2; ++ni) {
                acc1[mi][ni] = __builtin_amdgcn_mfma_i32_16x16x64_i8(faa[mi], fba[ni], acc1[mi][ni], 0, 0, 0);
                acc2[mi][ni] = __builtin_amdgcn_mfma_i32_16x16x64_i8(faa[mi], fbb[ni], acc2[mi][ni], 0, 0, 0);
                acc2[mi][ni] = __builtin_amdgcn_mfma_i32_16x16x64_i8(fab[mi], fba[ni], acc2[mi][ni], 0, 0, 0);
                acc3[mi][ni] = __builtin_amdgcn_mfma_i32_16x16x64_i8(fab[mi], fbb[ni], acc3[mi][ni], 0, 0, 0);
            }
        __builtin_amdgcn_s_setprio(0);
        __syncthreads();
        cur ^= 1;
    }

    // e = S_aa*2^-8 + (S_ab+S_ba)*2^-15 + S_bb*2^-22  (exact in quantized domain)
    int colw = lane & 15;
    int rowg = (lane >> 4) * 4;
#pragma unroll
    for (int mi = 0; mi < 2; ++mi)
#pragma unroll
        for (int ni = 0; ni < 2; ++ni) {
            int cb = c0 + wr + mi * 16 + rowg;
            int d  = d0 + wc + ni * 16 + colw;
#pragma unroll
            for (int r = 0; r < 4; ++r) {
                int c = cb + r;
                float v = (float)acc1[mi][ni][r] * 0.00390625f
                        + (float)acc2[mi][ni][r] * 3.0517578125e-05f
                        + (float)acc3[mi][ni][r] * 2.384185791015625e-07f;
                energy[((size_t)b * CCH + c) * CCH + d] = v;
                if (!diag)
                    energy[((size_t)b * CCH + d) * CCH + c] = v;
            }
        }
}

// ---------------- Kernel 2: softmin over rows; writes bf16 attn in-place ----------------
__global__ __launch_bounds__(256) void softmax_kernel(float* __restrict__ energy) {
    size_t row = blockIdx.x;
    float* e = energy + row * CCH;
    int tid = threadIdx.x;
    fx2 v = *(const fx2*)(e + 2 * tid);

    float m = fminf(v[0], v[1]);
#pragma unroll
    for (int off = 32; off; off >>= 1) m = fminf(m, __shfl_xor(m, off));
    __shared__ float redm[4];
    __shared__ float reds[4];
    if ((tid & 63) == 0) redm[tid >> 6] = m;
    __syncthreads();
    m = fminf(fminf(redm[0], redm[1]), fminf(redm[2], redm[3]));

    float w0 = __expf(m - v[0]);
    float w1 = __expf(m - v[1]);
    float s = w0 + w1;
#pragma unroll
    for (int off = 32; off; off >>= 1) s += __shfl_xor(s, off);
    if ((tid & 63) == 0) reds[tid >> 6] = s;
    __syncthreads();
    s = (reds[0] + reds[1]) + (reds[2] + reds[3]);
    float inv = 1.0f / s;
    unsigned uw = ((unsigned)(unsigned short)f2bf(w0 * inv)) |
                  (((unsigned)(unsigned short)f2bf(w1 * inv)) << 16);
    ((unsigned*)e)[tid] = uw;   // safe: all reads completed before barriers
}

// ---------------- Kernel 3: out = gamma * (attn @ q) + x ----------------
// 128x128 tile, BK=32, 4 waves each owning 64x64. 2-buffer (32 KiB) -> 4 blocks/CU.
// Epilogue: 16 x-loads in flight per mi block, then 16 plain stores (L2 write-combining).
__global__ __launch_bounds__(256, 4) void out_kernel(const float* __restrict__ x,
                                                     const short* __restrict__ attnb, // 1024-short rows
                                                     const short* __restrict__ xt,    // [n][c] bf16
                                                     const float* __restrict__ gamma,
                                                     float* __restrict__ out) {
    int orig = blockIdx.x;
    int blk  = (orig & 7) * 256 + (orig >> 3);   // 2048 = 8 x 256
    int b   = blk >> 7;
    int t   = blk & 127;
    int c0  = (t >> 5) * 128;
    int n0  = (t & 31) * 128;
    const float* xb = x + (size_t)b * CCH * NSP;
    const short* ab = attnb + (size_t)b * CCH * 1024;
    const short* qt = xt + (size_t)b * NSP * CCH;

    __shared__ short SA[2][128][32];    // 16 KiB
    __shared__ short SB[2][128][32];    // 16 KiB

    int tid  = threadIdx.x;
    int lane = tid & 63;
    int w    = tid >> 6;
    int wr   = (w >> 1) * 64;
    int wc   = (w & 1) * 64;

    int srow = lane >> 2;
    int gch  = (lane & 3) ^ ((lane >> 3) & 3);

    auto STAGE = [&](int buf, int kt) {
#pragma unroll
        for (int hf = 0; hf < 2; ++hf) {
            int rg = hf * 64 + w * 16;
            gload16(ab + (size_t)(c0 + rg + srow) * 1024 + kt * 32 + gch * 8, &SA[buf][rg][0]);
            gload16(qt + (size_t)(n0 + rg + srow) * 512  + kt * 32 + gch * 8, &SB[buf][rg][0]);
        }
    };

    fx4 acc[4][4];
#pragma unroll
    for (int i = 0; i < 4; i++)
#pragma unroll
        for (int j = 0; j < 4; j++) acc[i][j] = (fx4)(0.0f);

    STAGE(0, 0);
    __syncthreads();

    int h = lane >> 4;
    int cur = 0;
    const int NT = CCH / 32;            // 16
    for (int kt = 0; kt < NT; ++kt) {
        // issue next tile's loads first (max flight time under this step's MFMA)
        if (kt + 1 < NT) STAGE(cur ^ 1, kt + 1);

        bfx8 af[4], bf[4];
#pragma unroll
        for (int mi = 0; mi < 4; ++mi) {
            int r  = wr + mi * 16 + (lane & 15);
            af[mi] = *(const bfx8*)((const char*)&SA[cur][0][0] + r * 64 + ((h ^ ((r >> 1) & 3)) << 4));
        }
#pragma unroll
        for (int ni = 0; ni < 4; ++ni) {
            int r  = wc + ni * 16 + (lane & 15);
            bf[ni] = *(const bfx8*)((const char*)&SB[cur][0][0] + r * 64 + ((h ^ ((r >> 1) & 3)) << 4));
        }
        __builtin_amdgcn_s_setprio(1);
#pragma unroll
        for (int mi = 0; mi < 4; ++mi)
#pragma unroll
            for (int ni = 0; ni < 4; ++ni)
                acc[mi][ni] = __builtin_amdgcn_mfma_f32_16x16x32_bf16(af[mi], bf[ni], acc[mi][ni], 0, 0, 0);
        __builtin_amdgcn_s_setprio(0);
        __syncthreads();
        cur ^= 1;
    }

    float g = gamma[0];
    int colw = lane & 15;
    int rowg = (lane >> 4) * 4;
#pragma unroll
    for (int mi = 0; mi < 4; ++mi) {
        float xrow[4][4];               // 16 loads in flight before any store
#pragma unroll
        for (int r = 0; r < 4; ++r) {
            const float* xrowp = xb + (size_t)(c0 + wr + mi * 16 + rowg + r) * NSP;
#pragma unroll
            for (int ni = 0; ni < 4; ++ni)
                xrow[r][ni] = xrowp[n0 + wc + ni * 16 + colw];
        }
#pragma unroll
        for (int r = 0; r < 4; ++r) {
            int c = c0 + wr + mi * 16 + rowg + r;
#pragma unroll
            for (int ni = 0; ni < 4; ++ni) {
                int n = n0 + wc + ni * 16 + colw;
                out[((size_t)b * CCH + c) * NSP + n] = g * acc[mi][ni][r] + xrow[r][ni];
            }
        }
    }
}

extern "C" void kernel_launch(void* const* d_in, const int* in_sizes, int n_in,
                              void* d_out, int out_size, void* d_ws, size_t ws_size,
                              hipStream_t stream) {
    (void)in_sizes; (void)n_in; (void)out_size; (void)ws_size;
    const float* x     = (const float*)d_in[0];
    const float* gamma = (const float*)d_in[1];
    float*       out   = (float*)d_out;

    size_t nel = (size_t)BATCH * CCH * NSP;              // 33.5M
    // ws layout: xa(nel) | xb(nel) | xt(2*nel) | e0(16.8MB) = 151 MB
    char*  xap = (char*)d_ws;
    char*  xbp = xap + nel;
    short* xtp = (short*)(xap + 2 * nel);
    float* e0  = (float*)(xap + 4 * nel);

    fused_split_kernel<<<BATCH * 512, 256, 0, stream>>>(x, xap, xbp, xtp);
    energy_kernel     <<<BATCH * 36, 256, 0, stream>>>(xap, xbp, e0);
    softmax_kernel    <<<BATCH * CCH, 256, 0, stream>>>(e0);
    out_kernel        <<<BATCH * 128, 256, 0, stream>>>(x, (const short*)e0, xtp, gamma, out);
}